// Round 1
// baseline (340.536 us; speedup 1.0000x reference)
//
#include <hip/hip_runtime.h>
#include <cstdint>
#include <cstddef>

// ================= VQ layer: N=32768 pts, D=256, K=8192 codes ==================
// Pipeline: zero -> prepE (transpose + f16 split, MFMA-frag-permuted) -> e2
//        -> screen (f16 MFMA + packed top-2 argmin) -> rescan (candidates)
//        -> exact (fp64 on candidates) -> gather (+loss)
#define NPTS   32768
#define DDIM   256
#define KCOD   8192
#define NELEM  8388608            // NPTS*DDIM
#define BIAS   4096.0f            // keeps scaled scores positive for uint-packed compare
#define WINDOW 8.0f               // 2*delta'(=5.0) + packed truncation granularity + slack

typedef _Float16 half8 __attribute__((ext_vector_type(8)));
typedef float    f32x4 __attribute__((ext_vector_type(4)));

__device__ __forceinline__ unsigned umin_(unsigned a, unsigned b){ return a<b?a:b; }
__device__ __forceinline__ unsigned umax_(unsigned a, unsigned b){ return a>b?a:b; }

// ---------------------------------------------------------------- zero scratch
__global__ void k_zero(int* __restrict__ ccounts, int* __restrict__ flagcount,
                       float* __restrict__ out_loss) {
  int t = blockIdx.x*256 + threadIdx.x;
  if (t < NPTS) ccounts[t] = 0;
  if (t == 0) *flagcount = 0;
  if (t == 1) *out_loss = 0.0f;
}

// ------------------------------------------------- E prep: Et (fp32, [k][d]) +
// EhP: f16(16*E) permuted into MFMA B-fragment order:
//   chunk c (128 cols): [st(8)][cb(8)][q(4)][lp(16)][j(8)]  (16B per (q,lp) group)
__global__ void k_prepE(const float* __restrict__ E, _Float16* __restrict__ EhP,
                        float* __restrict__ Et) {
  int o  = blockIdx.x*256 + threadIdx.x;     // 262144 groups of 8 elements
  int lp = o & 15, q = (o>>4)&3, cb = (o>>6)&7, st = (o>>9)&7, c = o>>12;
  int k  = c*128 + cb*16 + lp;
  int d0 = st*32 + q*8;
  float v[8];
  #pragma unroll
  for (int j = 0; j < 8; ++j) v[j] = E[(size_t)(d0+j)*KCOD + k];
  float* et = Et + (size_t)k*DDIM + d0;
  *(float4*)(et)     = make_float4(v[0], v[1], v[2], v[3]);
  *(float4*)(et + 4) = make_float4(v[4], v[5], v[6], v[7]);
  half8 h;
  #pragma unroll
  for (int j = 0; j < 8; ++j) h[j] = (_Float16)(16.0f * v[j]);
  *(half8*)(EhP + (size_t)o*8) = h;
}

// --------------------------------------------- e2p[k] = 256*||E_k||^2 + BIAS
__global__ void k_e2(const float* __restrict__ Et, float* __restrict__ e2p) {
  int lane = threadIdx.x & 63, wid = threadIdx.x >> 6;
  int k = blockIdx.x*4 + wid;
  float4 v = *((const float4*)(Et + (size_t)k*DDIM) + lane);
  float s = v.x*v.x + v.y*v.y + v.z*v.z + v.w*v.w;
  #pragma unroll
  for (int off = 1; off < 64; off <<= 1) s += __shfl_xor(s, off);
  if (lane == 0) e2p[k] = 256.0f*s + BIAS;
}

// --------------------------------------------------------- P1: f16 MFMA screen
// block=256 (4 waves as 2x2), BM=64 rows, 64 chunks of 128 cols, D=256 K-loop.
// A frags register-resident; B via 64KB LDS (linear copy, frag order).
__launch_bounds__(256, 2)
__global__ void k_screen(const float* __restrict__ X, const _Float16* __restrict__ EhP,
                         const float* __restrict__ e2p, float* __restrict__ m1s,
                         int* __restrict__ idx, int* __restrict__ flaglist,
                         int* __restrict__ flagcount)
{
  __shared__ __align__(16) _Float16 Bsh[32768];   // 64 KB
  const int tid = threadIdx.x;
  const int lane = tid & 63, wid = tid >> 6;
  const int q = lane >> 4, lp = lane & 15;
  const int wr = wid >> 1, wc = wid & 1;
  const int rowbase = blockIdx.x*64 + wr*32;

  half8 af[2][8];
  #pragma unroll
  for (int mb = 0; mb < 2; ++mb) {
    const float* xr = X + (size_t)(rowbase + mb*16 + lp)*DDIM;
    #pragma unroll
    for (int st = 0; st < 8; ++st) {
      const float* p = xr + st*32 + q*8;
      float4 v0 = *(const float4*)p;
      float4 v1 = *(const float4*)(p + 4);
      half8 h;
      h[0]=(_Float16)(16.f*v0.x); h[1]=(_Float16)(16.f*v0.y);
      h[2]=(_Float16)(16.f*v0.z); h[3]=(_Float16)(16.f*v0.w);
      h[4]=(_Float16)(16.f*v1.x); h[5]=(_Float16)(16.f*v1.y);
      h[6]=(_Float16)(16.f*v1.z); h[7]=(_Float16)(16.f*v1.w);
      af[mb][st] = h;
    }
  }

  unsigned m1p[2][4], m2p[2][4];
  #pragma unroll
  for (int mb=0;mb<2;++mb)
    #pragma unroll
    for (int r=0;r<4;++r) { m1p[mb][r]=0xFFFFFFFFu; m2p[mb][r]=0xFFFFFFFFu; }

  for (int c = 0; c < 64; ++c) {
    __syncthreads();
    { // stage 64 KB chunk, linear copy (frag order already baked in)
      const uint4* src = (const uint4*)(EhP + (size_t)c*32768) + tid;
      uint4* dst = (uint4*)Bsh + tid;
      #pragma unroll
      for (int r = 0; r < 16; ++r) dst[r*256] = src[r*256];
    }
    __syncthreads();

    f32x4 acc[2][4];
    #pragma unroll
    for (int mb=0;mb<2;++mb)
      #pragma unroll
      for (int nb=0;nb<4;++nb) { f32x4 z = {0.f,0.f,0.f,0.f}; acc[mb][nb] = z; }

    #pragma unroll
    for (int st = 0; st < 8; ++st) {
      half8 bf[4];
      #pragma unroll
      for (int nb = 0; nb < 4; ++nb)
        bf[nb] = *(const half8*)(Bsh + ((st*8 + wc*4 + nb)*512 + lane*8));
      #pragma unroll
      for (int nb = 0; nb < 4; ++nb)
        #pragma unroll
        for (int mb = 0; mb < 2; ++mb)
          acc[mb][nb] = __builtin_amdgcn_mfma_f32_16x16x32_f16(af[mb][st], bf[nb], acc[mb][nb], 0, 0, 0);
    }

    const int colbase = c*128 + wc*64 + lp;
    #pragma unroll
    for (int nb = 0; nb < 4; ++nb) {
      const int col = colbase + nb*16;
      const float e2v = e2p[col];
      #pragma unroll
      for (int mb = 0; mb < 2; ++mb)
        #pragma unroll
        for (int r = 0; r < 4; ++r) {
          float s = fmaf(-2.0f, acc[mb][nb][r], e2v);
          unsigned u = (__float_as_uint(s) & 0xFFFFE000u) | (unsigned)col;
          m2p[mb][r] = umin_(m2p[mb][r], umax_(m1p[mb][r], u));
          m1p[mb][r] = umin_(m1p[mb][r], u);
        }
    }
  }

  // merge across the 16 lanes (lp) of each quad
  #pragma unroll
  for (int off = 1; off <= 8; off <<= 1) {
    #pragma unroll
    for (int mb=0;mb<2;++mb)
      #pragma unroll
      for (int r=0;r<4;++r) {
        unsigned o1 = (unsigned)__shfl_xor((int)m1p[mb][r], off);
        unsigned o2 = (unsigned)__shfl_xor((int)m2p[mb][r], off);
        m2p[mb][r] = umin_(umin_(m2p[mb][r], o2), umax_(m1p[mb][r], o1));
        m1p[mb][r] = umin_(m1p[mb][r], o1);
      }
  }
  __syncthreads();
  unsigned* S = (unsigned*)Bsh;
  if (lp == 0) {
    #pragma unroll
    for (int mb=0;mb<2;++mb)
      #pragma unroll
      for (int r=0;r<4;++r) {
        int rl = mb*16 + q*4 + r;
        S[wid*64 + rl*2]     = m1p[mb][r];
        S[wid*64 + rl*2 + 1] = m2p[mb][r];
      }
  }
  __syncthreads();
  if (tid < 64) {   // merge wc halves, write results
    int wrp = tid >> 5, rl = tid & 31;
    unsigned a1 = S[(wrp*2+0)*64 + rl*2], a2 = S[(wrp*2+0)*64 + rl*2+1];
    unsigned b1 = S[(wrp*2+1)*64 + rl*2], b2 = S[(wrp*2+1)*64 + rl*2+1];
    unsigned m1 = umin_(a1, b1);
    unsigned m2 = umin_(umin_(a2, b2), umax_(a1, b1));
    int g = blockIdx.x*64 + wrp*32 + rl;
    idx[g] = (int)(m1 & 0x1FFFu);
    float m1f = __uint_as_float(m1 & 0xFFFFE000u);
    float m2f = __uint_as_float(m2 & 0xFFFFE000u);
    m1s[g] = m1f;
    if (m2f - m1f < WINDOW) {
      int p = atomicAdd(flagcount, 1);
      flaglist[p] = g;
    }
  }
}

// -------------------------------- P2: rescan flagged rows, collect candidates
// grid 512 = 32 batch-slots x 16 K-slices (4 chunks each)
__launch_bounds__(256, 2)
__global__ void k_rescan(const float* __restrict__ X, const _Float16* __restrict__ EhP,
                         const float* __restrict__ e2p, const float* __restrict__ m1s,
                         const int* __restrict__ flaglist, const int* __restrict__ flagcount,
                         int* __restrict__ ccounts, int* __restrict__ candbuf)
{
  __shared__ __align__(16) _Float16 Bsh[32768];
  const int tid = threadIdx.x, lane = tid & 63, wid = tid >> 6;
  const int q = lane >> 4, lp = lane & 15;
  const int wr = wid >> 1, wc = wid & 1;
  const int slice = blockIdx.x & 15, bslot = blockIdx.x >> 4;
  const int cnt = *flagcount;

  for (int batch = bslot; batch*64 < cnt; batch += 32) {
    const int base = batch*64 + wr*32;
    int ga[2];
    #pragma unroll
    for (int mb=0;mb<2;++mb) {
      int fi = base + mb*16 + lp;
      ga[mb] = (fi < cnt) ? flaglist[fi] : 0;
    }
    float thr[2][4]; int gs[2][4];
    #pragma unroll
    for (int mb=0;mb<2;++mb)
      #pragma unroll
      for (int r=0;r<4;++r) {
        int fi = base + mb*16 + q*4 + r;
        if (fi < cnt) { int g = flaglist[fi]; gs[mb][r] = g; thr[mb][r] = m1s[g] + WINDOW; }
        else          { gs[mb][r] = 0; thr[mb][r] = -3.0e38f; }
      }
    half8 af[2][8];
    #pragma unroll
    for (int mb = 0; mb < 2; ++mb) {
      const float* xr = X + (size_t)ga[mb]*DDIM;
      #pragma unroll
      for (int st = 0; st < 8; ++st) {
        const float* p = xr + st*32 + q*8;
        float4 v0 = *(const float4*)p;
        float4 v1 = *(const float4*)(p + 4);
        half8 h;
        h[0]=(_Float16)(16.f*v0.x); h[1]=(_Float16)(16.f*v0.y);
        h[2]=(_Float16)(16.f*v0.z); h[3]=(_Float16)(16.f*v0.w);
        h[4]=(_Float16)(16.f*v1.x); h[5]=(_Float16)(16.f*v1.y);
        h[6]=(_Float16)(16.f*v1.z); h[7]=(_Float16)(16.f*v1.w);
        af[mb][st] = h;
      }
    }
    for (int cc4 = 0; cc4 < 4; ++cc4) {
      const int c = slice*4 + cc4;
      __syncthreads();
      { const uint4* src = (const uint4*)(EhP + (size_t)c*32768) + tid;
        uint4* dst = (uint4*)Bsh + tid;
        #pragma unroll
        for (int r = 0; r < 16; ++r) dst[r*256] = src[r*256];
      }
      __syncthreads();
      f32x4 acc[2][4];
      #pragma unroll
      for (int mb=0;mb<2;++mb)
        #pragma unroll
        for (int nb=0;nb<4;++nb) { f32x4 z = {0.f,0.f,0.f,0.f}; acc[mb][nb] = z; }
      #pragma unroll
      for (int st = 0; st < 8; ++st) {
        half8 bf[4];
        #pragma unroll
        for (int nb = 0; nb < 4; ++nb)
          bf[nb] = *(const half8*)(Bsh + ((st*8 + wc*4 + nb)*512 + lane*8));
        #pragma unroll
        for (int nb = 0; nb < 4; ++nb)
          #pragma unroll
          for (int mb = 0; mb < 2; ++mb)
            acc[mb][nb] = __builtin_amdgcn_mfma_f32_16x16x32_f16(af[mb][st], bf[nb], acc[mb][nb], 0, 0, 0);
      }
      const int colbase = c*128 + wc*64 + lp;
      #pragma unroll
      for (int nb = 0; nb < 4; ++nb) {
        const int col = colbase + nb*16;
        const float e2v = e2p[col];
        #pragma unroll
        for (int mb = 0; mb < 2; ++mb)
          #pragma unroll
          for (int r = 0; r < 4; ++r) {
            float s = fmaf(-2.0f, acc[mb][nb][r], e2v);
            if (s < thr[mb][r]) {
              int g = gs[mb][r];
              int slot = atomicAdd(&ccounts[g], 1);
              if (slot < 16) candbuf[g*16 + slot] = col;
            }
          }
      }
    }
  }
}

// -------------------------------------- P3: exact fp64 argmin over candidates
__global__ void k_exact(const float* __restrict__ X, const float* __restrict__ Et,
                        const int* __restrict__ flaglist, const int* __restrict__ flagcount,
                        const int* __restrict__ ccounts, const int* __restrict__ candbuf,
                        int* __restrict__ idx)
{
  const int cnt = *flagcount;
  const int lane = threadIdx.x & 63;
  const int w = blockIdx.x*4 + (threadIdx.x >> 6);
  for (int i = w; i < cnt; i += 256) {
    const int g = flaglist[i];
    const int cc = ccounts[g];
    double best = 1.0e300; int bestk = 0x7FFFFFFF;
    if (cc <= 16) {
      float4 xv = *(const float4*)(X + (size_t)g*DDIM + lane*4);
      for (int c = 0; c < cc; ++c) {
        int k = candbuf[g*16 + c];
        float4 ev = *(const float4*)(Et + (size_t)k*DDIM + lane*4);
        double d0 = (double)xv.x - (double)ev.x, d1 = (double)xv.y - (double)ev.y;
        double d2 = (double)xv.z - (double)ev.z, d3 = (double)xv.w - (double)ev.w;
        double s = d0*d0 + d1*d1 + d2*d2 + d3*d3;
        #pragma unroll
        for (int off = 1; off < 64; off <<= 1) s += __shfl_xor(s, off);
        if (s < best || (s == best && k < bestk)) { best = s; bestk = k; }
      }
    } else {  // overflow fallback: full exact scan (statistically ~never)
      double bb = 1.0e300; int bk = 0x7FFFFFFF;
      for (int k = lane; k < KCOD; k += 64) {
        double s = 0.0;
        for (int d = 0; d < DDIM; ++d) {
          double df = (double)X[(size_t)g*DDIM + d] - (double)Et[(size_t)k*DDIM + d];
          s += df*df;
        }
        if (s < bb || (s == bb && k < bk)) { bb = s; bk = k; }
      }
      #pragma unroll
      for (int off = 1; off < 64; off <<= 1) {
        double ob = __shfl_xor(bb, off); int ok = __shfl_xor(bk, off);
        if (ob < bb || (ob == bb && ok < bk)) { bb = ob; bk = ok; }
      }
      best = bb; bestk = bk;
    }
    if (lane == 0 && bestk != 0x7FFFFFFF) idx[g] = bestk;
  }
}

// -------------------------------------------------- P4: gather output + loss
__global__ void k_gather(const float* __restrict__ X, const float* __restrict__ Et,
                         const int* __restrict__ idx, float* __restrict__ out)
{
  const int lane = threadIdx.x & 63, wid = threadIdx.x >> 6;
  float lsum = 0.0f;
  for (int i = 0; i < 16; ++i) {
    int n = blockIdx.x*64 + i*4 + wid;
    int k = idx[n];
    float4 xv = *(const float4*)(X  + (size_t)n*DDIM + lane*4);
    float4 ev = *(const float4*)(Et + (size_t)k*DDIM + lane*4);
    *(float4*)(out + (size_t)n*DDIM + lane*4) = ev;   // quantized_st fwd value == q exactly
    float d0 = ev.x-xv.x, d1 = ev.y-xv.y, d2 = ev.z-xv.z, d3 = ev.w-xv.w;
    lsum += d0*d0 + d1*d1 + d2*d2 + d3*d3;
  }
  #pragma unroll
  for (int off = 1; off < 64; off <<= 1) lsum += __shfl_xor(lsum, off);
  if (lane == 0) atomicAdd(out + (size_t)NELEM, lsum * (1.25f/8388608.0f));
}

// ================================ launch ======================================
extern "C" void kernel_launch(void* const* d_in, const int* in_sizes, int n_in,
                              void* d_out, int out_size, void* d_ws, size_t ws_size,
                              hipStream_t stream)
{
  const float* X = (const float*)d_in[0];   // [32768][256]
  const float* E = (const float*)d_in[1];   // [256][8192]
  float* out = (float*)d_out;               // [8388608 quantized][1 loss]
  char* ws = (char*)d_ws;

  float*     Et        = (float*)(ws);                               // 8 MB
  _Float16*  EhP       = (_Float16*)(ws + 8388608);                  // 4 MB
  float*     e2p       = (float*)(ws + 12582912);                    // 32 KB
  float*     m1s       = (float*)(ws + 12615680);                    // 128 KB
  int*       idx       = (int*)(ws + 12746752);                      // 128 KB
  int*       flaglist  = (int*)(ws + 12877824);                      // 128 KB
  int*       ccounts   = (int*)(ws + 13008896);                      // 128 KB
  int*       candbuf   = (int*)(ws + 13139968);                      // 2 MB
  int*       flagcount = (int*)(ws + 15237120);                      // 4 B
  if (ws_size < (size_t)15237124) return;  // insufficient scratch -> fail loudly

  dim3 B(256);
  k_zero  <<<dim3(128),  B, 0, stream>>>(ccounts, flagcount, out + NELEM);
  k_prepE <<<dim3(1024), B, 0, stream>>>(E, EhP, Et);
  k_e2    <<<dim3(2048), B, 0, stream>>>(Et, e2p);
  k_screen<<<dim3(512),  B, 0, stream>>>(X, EhP, e2p, m1s, idx, flaglist, flagcount);
  k_rescan<<<dim3(512),  B, 0, stream>>>(X, EhP, e2p, m1s, flaglist, flagcount, ccounts, candbuf);
  k_exact <<<dim3(64),   B, 0, stream>>>(X, Et, flaglist, flagcount, ccounts, candbuf, idx);
  k_gather<<<dim3(512),  B, 0, stream>>>(X, Et, idx, out);
}